// Round 5
// baseline (94.391 us; speedup 1.0000x reference)
//
#include <hip/hip_runtime.h>

#define SS 256
#define HH 1024
#define RH 512

typedef __attribute__((ext_vector_type(8))) short short8;
typedef __attribute__((ext_vector_type(4))) float f32x4;

// Convert 8 contiguous f32 -> 8 bf16 (packed, RNE) for an MFMA fragment.
__device__ __forceinline__ short8 load_frag_bf16(const float* p) {
    f32x4 lo = *reinterpret_cast<const f32x4*>(p);
    f32x4 hi = *reinterpret_cast<const f32x4*>(p + 4);
    union { int i[4]; short8 s; } u;
    asm("v_cvt_pk_bf16_f32 %0, %1, %2" : "=v"(u.i[0]) : "v"(lo.x), "v"(lo.y));
    asm("v_cvt_pk_bf16_f32 %0, %1, %2" : "=v"(u.i[1]) : "v"(lo.z), "v"(lo.w));
    asm("v_cvt_pk_bf16_f32 %0, %1, %2" : "=v"(u.i[2]) : "v"(hi.x), "v"(hi.y));
    asm("v_cvt_pk_bf16_f32 %0, %1, %2" : "=v"(u.i[3]) : "v"(hi.z), "v"(hi.w));
    return u.s;
}

// Roles by blockIdx.x:
//   [0,128):   A  = en @ W1^T (M=256,N=512,K=1024), 32x32 block tile, 16x16/wave
//   [128,256): wd = de @ W2^T (M=256,N=512,K=512),  same tiling
//   [256,320): gates[j] = sigmoid(concat(e[t[j]], e[j]) . Wg), wave-per-j
__global__ __launch_bounds__(256) void prep_kernel(
    const float* __restrict__ en, const float* __restrict__ de,
    const int* __restrict__ target, const float* __restrict__ W1,
    const float* __restrict__ W2, const float* __restrict__ Wg,
    float* __restrict__ Aout, float* __restrict__ wdout,
    float* __restrict__ gates)
{
    const int b = blockIdx.x;
    const int tid = threadIdx.x;
    const int w = tid >> 6;
    const int lane = tid & 63;

    if (b < 256) {
        const float* X; const float* Y; float* C; int K; int tb;
        if (b < 128) { X = en; Y = W1; C = Aout;  K = HH; tb = b; }
        else         { X = de; Y = W2; C = wdout; K = RH; tb = b - 128; }
        // 32x32 block tile: 8 (M) x 16 (N) block-tiles; wave = 16x16 quadrant
        const int m0 = (tb >> 4) * 32 + (w >> 1) * 16;
        const int n0 = (tb & 15) * 32 + (w & 1) * 16;
        const int fr = lane & 15;          // row within 16-row panel
        const int kf = (lane >> 4) * 8;    // k offset of this lane's 8 elems

        const float* xp = X + (size_t)(m0 + fr) * K + kf;
        const float* yp = Y + (size_t)(n0 + fr) * K + kf;

        f32x4 acc0 = {0.f, 0.f, 0.f, 0.f};
        f32x4 acc1 = {0.f, 0.f, 0.f, 0.f};
        #pragma unroll 4
        for (int k0 = 0; k0 < K; k0 += 64) {
            short8 a0 = load_frag_bf16(xp + k0);
            short8 b0 = load_frag_bf16(yp + k0);
            short8 a1 = load_frag_bf16(xp + k0 + 32);
            short8 b1 = load_frag_bf16(yp + k0 + 32);
            acc0 = __builtin_amdgcn_mfma_f32_16x16x32_bf16(a0, b0, acc0, 0, 0, 0);
            acc1 = __builtin_amdgcn_mfma_f32_16x16x32_bf16(a1, b1, acc1, 0, 0, 0);
        }
        f32x4 acc = acc0 + acc1;

        // C/D layout: col = lane&15, row = (lane>>4)*4 + reg   [measured m89/m91]
        const int ccol = lane & 15;
        const int crow = (lane >> 4) * 4;
        #pragma unroll
        for (int r = 0; r < 4; r++)
            C[(size_t)(m0 + crow + r) * RH + n0 + ccol] = acc[r];
    } else {
        // gates: one wave per j
        const int j = (b - 256) * 4 + w;
        const int tj = target[j];
        const float* e1 = en + (size_t)tj * HH;  // en_l row
        const float* e2 = en + (size_t)j * HH;
        const int h0 = lane * 16;
        float acc = 0.f;
        #pragma unroll
        for (int q = 0; q < 4; q++) {
            f32x4 a  = *reinterpret_cast<const f32x4*>(e1 + h0 + q * 4);
            f32x4 g1 = *reinterpret_cast<const f32x4*>(Wg + h0 + q * 4);
            acc += a.x * g1.x + a.y * g1.y + a.z * g1.z + a.w * g1.w;
            f32x4 c2 = *reinterpret_cast<const f32x4*>(e2 + h0 + q * 4);
            f32x4 g2 = *reinterpret_cast<const f32x4*>(Wg + HH + h0 + q * 4);
            acc += c2.x * g2.x + c2.y * g2.y + c2.z * g2.z + c2.w * g2.w;
        }
        #pragma unroll
        for (int off = 32; off > 0; off >>= 1)
            acc += __shfl_down(acc, off, 64);
        if (lane == 0)
            gates[j] = 1.f / (1.f + __expf(-acc));
    }
}

// att[i,j] = sum_r relu(A[j,r] + c[i,j]*A[t[j],r] + wd[i,r]) * V[r]
// 512 blocks = 16 i-panels (16 i each) x 32 j-octets; 512 threads = 8 waves,
// wave owns one j. wd panel (16 x 512 f32 = 32 KB) staged in LDS once per
// block, reused by all 8 waves (L2 traffic 128 MB -> ~32 MB). Lane l owns
// r in [l*8, l*8+8): A[j], A[tj], V in registers. Butterfly r-reduce.
__global__ __launch_bounds__(512) void att_kernel(
    const float* __restrict__ A, const float* __restrict__ wd,
    const float* __restrict__ gates, const int* __restrict__ target,
    const float* __restrict__ mask, const float* __restrict__ V,
    float* __restrict__ out)
{
    __shared__ float smem[16 * RH];                       // 32 KB
    const int b = blockIdx.x;
    const int i0 = (b >> 5) << 4;                         // 16 i-panels of 16
    const int j  = ((b & 31) << 3) + (threadIdx.x >> 6);  // wave -> j
    const int l  = threadIdx.x & 63;
    const int t  = threadIdx.x;

    // stage wd[i0 .. i0+16) into LDS, fully coalesced (2048 x f32x4)
    {
        const f32x4* src = reinterpret_cast<const f32x4*>(wd + (size_t)i0 * RH);
        f32x4* dst = reinterpret_cast<f32x4*>(smem);
        #pragma unroll
        for (int k = 0; k < 4; k++)
            dst[k * 512 + t] = src[k * 512 + t];
    }

    const int   tj = target[j];
    const float gj = gates[j];

    const float* Ar = A + (size_t)j  * RH + l * 8;
    const float* Br = A + (size_t)tj * RH + l * 8;
    const f32x4 a0 = *reinterpret_cast<const f32x4*>(Ar);
    const f32x4 a1 = *reinterpret_cast<const f32x4*>(Ar + 4);
    const f32x4 b0 = *reinterpret_cast<const f32x4*>(Br);
    const f32x4 b1 = *reinterpret_cast<const f32x4*>(Br + 4);
    const f32x4 v0 = *reinterpret_cast<const f32x4*>(V + l * 8);
    const f32x4 v1 = *reinterpret_cast<const f32x4*>(V + l * 8 + 4);

    // lane l (l<16 meaningful) holds mask[i0+l, j] * g[j]
    const float mval = mask[(i0 + (l & 15)) * SS + j] * gj;

    __syncthreads();

    const f32x4* wp = reinterpret_cast<const f32x4*>(smem) + l * 2;
    float keep = 0.f;
    #pragma unroll 4
    for (int ii = 0; ii < 16; ii++) {
        const float c = __shfl(mval, ii, 64);
        const f32x4 w0 = wp[0];
        const f32x4 w1 = wp[1];
        wp += RH / 4;
        float p;
        p  = fmaxf(fmaf(c, b0.x, a0.x) + w0.x, 0.f) * v0.x;
        p += fmaxf(fmaf(c, b0.y, a0.y) + w0.y, 0.f) * v0.y;
        p += fmaxf(fmaf(c, b0.z, a0.z) + w0.z, 0.f) * v0.z;
        p += fmaxf(fmaf(c, b0.w, a0.w) + w0.w, 0.f) * v0.w;
        p += fmaxf(fmaf(c, b1.x, a1.x) + w1.x, 0.f) * v1.x;
        p += fmaxf(fmaf(c, b1.y, a1.y) + w1.y, 0.f) * v1.y;
        p += fmaxf(fmaf(c, b1.z, a1.z) + w1.z, 0.f) * v1.z;
        p += fmaxf(fmaf(c, b1.w, a1.w) + w1.w, 0.f) * v1.w;
        // butterfly reduce across 64 lanes
        p += __shfl_xor(p, 32, 64);
        p += __shfl_xor(p, 16, 64);
        p += __shfl_xor(p,  8, 64);
        p += __shfl_xor(p,  4, 64);
        p += __shfl_xor(p,  2, 64);
        p += __shfl_xor(p,  1, 64);
        keep = (l == ii) ? p : keep;   // collect result ii in lane ii
    }
    if (l < 16)
        out[(size_t)(i0 + l) * SS + j] = keep;
}

extern "C" void kernel_launch(void* const* d_in, const int* in_sizes, int n_in,
                              void* d_out, int out_size, void* d_ws, size_t ws_size,
                              hipStream_t stream) {
    const float* en     = (const float*)d_in[0];   // (1,256,1024)
    const float* de     = (const float*)d_in[1];   // (1,256,512)
    const int*   target = (const int*)  d_in[2];   // (256,)
    const float* mask_  = (const float*)d_in[3];   // (256,256)
    const float* W1     = (const float*)d_in[4];   // (512,1024)
    const float* W2     = (const float*)d_in[5];   // (512,512)
    const float* V      = (const float*)d_in[6];   // (512,)
    const float* Wg     = (const float*)d_in[7];   // (2048,)
    float* out = (float*)d_out;                    // (1,256,256)

    float* A     = (float*)d_ws;                   // 256*512 f32
    float* wd    = A + SS * RH;                    // 256*512 f32
    float* gates = wd + SS * RH;                   // 256 f32

    prep_kernel<<<320, 256, 0, stream>>>(en, de, target, W1, W2, Wg, A, wd, gates);
    att_kernel<<<512, 512, 0, stream>>>(A, wd, gates, target, mask_, V, out);
}